// Round 4
// baseline (969.559 us; speedup 1.0000x reference)
//
#include <hip/hip_runtime.h>
#include <math.h>

// Problem constants (fixed-shape problem)
#define NN 131072   // nodes
#define G  256      // groups
#define E  384      // embed
#define H  6        // heads
#define DH 64       // head dim
#define OUTD 256    // output dim
#define MAXN 1024   // max segment length

// Workspace layout (float indices)
#define WS_QK   0                       // 6*384 folded q@Wk
#define WS_OFF  2432                    // 256 int32 segment offsets
#define WS_WVT  12288                   // 384x384 Wv^T [e][i]
#define WS_WOT  (WS_WVT + E*E)          // 384x384 Wo^T [e][i]
#define WS_WPT  (WS_WOT + E*E)          // 384x256 Wp^T [e][o]

// ---------------------------------------------------------------------------
// K_PREP: single launch, 133 blocks, three roles (independent):
//   block 0      : segment-offset scan
//   blocks 1..36 : qk[h][e] = sum_d qv[h,d]*Wk[h*64+d][e]  (qv computed
//                  inline per block: 64 rows of 0.125*(Wq@query+bq) -- the
//                  redundancy is ~25K MACs/block, trivial; removes the
//                  cross-kernel dependency that forced 3 launches)
//   blocks 37..132: transpose Wv, Wo, Wp into ws (64x64 LDS tiles)
// ---------------------------------------------------------------------------
__global__ __launch_bounds__(256) void k_prep(
    const int* __restrict__ sizes, const float* __restrict__ query,
    const float* __restrict__ Wq, const float* __restrict__ bq,
    const float* __restrict__ Wk, const float* __restrict__ Wv,
    const float* __restrict__ Wo, const float* __restrict__ Wp,
    float* __restrict__ wsf) {
  const int b = blockIdx.x;
  const int tid = threadIdx.x;
  if (b == 0) {
    __shared__ int s_scan[G];
    const int sz = sizes[tid];
    s_scan[tid] = sz;
    __syncthreads();
    for (int d = 1; d < G; d <<= 1) {
      int t = (tid >= d) ? s_scan[tid - d] : 0;
      __syncthreads();
      s_scan[tid] += t;
      __syncthreads();
    }
    ((int*)(wsf + WS_OFF))[tid] = s_scan[tid] - sz;    // exclusive node offset
  } else if (b <= 36) {
    const int h = (b - 1) / 6, ec = (b - 1) % 6;
    __shared__ float qv_s[64];
    __shared__ float qps[256];
    __shared__ float ps[256];
    {  // inline qv rows h*64..h*64+63: thread (r,q) does a 96-elem quarter
      const int r = tid >> 2, q = tid & 3;
      const int row = h * 64 + r;
      float a = 0.f;
#pragma unroll 4
      for (int j = 0; j < 96; j++)
        a += Wq[(size_t)row * E + q * 96 + j] * query[q * 96 + j];
      qps[tid] = a;
    }
    __syncthreads();
    if (tid < 64)
      qv_s[tid] = 0.125f * (qps[tid * 4] + qps[tid * 4 + 1] +
                            qps[tid * 4 + 2] + qps[tid * 4 + 3] +
                            bq[h * 64 + tid]);
    __syncthreads();
    const int el = tid & 63, dq = tid >> 6;
    float a = 0.f;
#pragma unroll 4
    for (int d = dq * 16; d < dq * 16 + 16; d++)
      a += qv_s[d] * Wk[(size_t)(h * 64 + d) * E + ec * 64 + el];
    ps[tid] = a;
    __syncthreads();
    if (tid < 64)
      wsf[WS_QK + h * E + ec * 64 + tid] =
          ps[tid] + ps[64 + tid] + ps[128 + tid] + ps[192 + tid];
  } else {
    __shared__ float s[64][65];
    const int t = b - 37;                        // 0..95
    const float* src;
    float* dst;
    int R, tr, tc;
    if (t < 36)      { src = Wv; dst = wsf + WS_WVT; R = 384; tr = t / 6;        tc = t % 6; }
    else if (t < 72) { src = Wo; dst = wsf + WS_WOT; R = 384; tr = (t - 36) / 6; tc = (t - 36) % 6; }
    else             { src = Wp; dst = wsf + WS_WPT; R = 256; tr = (t - 72) / 6; tc = (t - 72) % 6; }
    const int r0 = tr * 64, c0 = tc * 64;
#pragma unroll
    for (int k = 0; k < 16; k++) {
      int idx = k * 256 + tid;
      int r = idx >> 6, cc = idx & 63;
      s[r][cc] = src[(size_t)(r0 + r) * E + c0 + cc];
    }
    __syncthreads();
#pragma unroll
    for (int k = 0; k < 16; k++) {
      int idx = k * 256 + tid;
      int cc = idx >> 6, r = idx & 63;
      dst[(size_t)(c0 + cc) * R + r0 + r] = s[r][cc];
    }
  }
}

// ---------------------------------------------------------------------------
// Wave-wide butterfly sum.  Steps xor1/2/4/8 via DPP (VALU pipe); xor16/32
// via shuffle (LDS pipe).
// ---------------------------------------------------------------------------
template <int CTRL>
__device__ __forceinline__ float dpp_radd(float v) {
  int t = __builtin_amdgcn_update_dpp(0, __float_as_int(v), CTRL, 0xf, 0xf, true);
  return v + __int_as_float(t);
}
__device__ __forceinline__ float wave_sum64(float v) {
  v = dpp_radd<0xB1>(v);   // quad_perm [1,0,3,2]  : xor 1
  v = dpp_radd<0x4E>(v);   // quad_perm [2,3,0,1]  : xor 2
  v = dpp_radd<0x141>(v);  // row_half_mirror      : xor 4
  v = dpp_radd<0x140>(v);  // row_mirror           : xor 8
  v += __shfl_xor(v, 16, 64);
  v += __shfl_xor(v, 32, 64);
  return v;
}

// ---------------------------------------------------------------------------
// K12G v9: fully fused per-group kernel, 1024 threads (16 waves) per block.
// v8 post-mortem: occupancy 23% ~= mean/max group ratio (tail groups set the
// wall), depth-1 dword prefetch left ~300cyc/node latency residual.
// Changes: 16 waves (896-node tail: 56 iters/wave vs 75); depth-2 rotating
// prefetch; per-node loads = 1 float4 + 1 float2 (2 instrs, 24B/lane,
// coalesced 1024B/512B segments).  Lane column map: j<4 -> 4*lane+j,
// j>=4 -> 256+2*lane+(j-4).  VGPR budget ~102 state + temps < 128 cap.
// ---------------------------------------------------------------------------
__global__ __launch_bounds__(1024, 4) void k12g_fused(
    const float* __restrict__ x, const int* __restrict__ sizes,
    const float* __restrict__ bv, const float* __restrict__ bo,
    const float* __restrict__ bp, float* __restrict__ out,
    const float* __restrict__ wsf) {
  __shared__ float xsl[4][H * E];      // 36.9 KB accumulation slices
  __shared__ float ps[768];
  __shared__ float pooled[E];
  __shared__ float om[E];
  __shared__ float msh[16][H], lsh[16][H], wgts[16][H];
  __shared__ float linv[H];

  const int tid = threadIdx.x;
  const int lane = tid & 63;
  const int w = tid >> 6;              // wave 0..15
  const int g = blockIdx.x;
  const int sz = sizes[g];
  const int n0 = ((const int*)(wsf + WS_OFF))[g];

  // per-lane qk fragment matching the float4+float2 column map
  float qk[6][6];
#pragma unroll
  for (int h = 0; h < 6; h++) {
    const float4 q4 = *(const float4*)&wsf[WS_QK + h * E + 4 * lane];
    const float2 q2 = *(const float2*)&wsf[WS_QK + h * E + 256 + 2 * lane];
    qk[h][0] = q4.x; qk[h][1] = q4.y; qk[h][2] = q4.z; qk[h][3] = q4.w;
    qk[h][4] = q2.x; qk[h][5] = q2.y;
  }

  float m[6], l[6], acc[6][6];
#pragma unroll
  for (int h = 0; h < 6; h++) {
    m[h] = -3.0e38f;
    l[h] = 0.f;
#pragma unroll
    for (int k = 0; k < 6; k++) acc[h][k] = 0.f;
  }

  // ---- phase 1: wave w handles nodes w, w+16, w+32, ... ----
  const float* xp = x + (size_t)(n0 + w) * E;
  const int cnt = (sz > w) ? ((sz - w + 15) / 16) : 0;

  float x0[6], x1[6], x2[6];
#define LOADX(buf, i)                                              \
  {                                                                \
    const float* p_ = xp + (size_t)(i) * (16 * E);                 \
    const float4 v4_ = *(const float4*)(p_ + 4 * lane);            \
    const float2 v2_ = *(const float2*)(p_ + 256 + 2 * lane);      \
    buf[0] = v4_.x; buf[1] = v4_.y; buf[2] = v4_.z; buf[3] = v4_.w;\
    buf[4] = v2_.x; buf[5] = v2_.y;                                \
  }
#define COMPUTE(xv)                                                          \
  {                                                                          \
    float sr[6];                                                             \
    _Pragma("unroll") for (int h_ = 0; h_ < 6; h_++) {                       \
      float a_ = qk[h_][0] * xv[0];                                          \
      _Pragma("unroll") for (int k_ = 1; k_ < 6; k_++)                       \
          a_ = fmaf(qk[h_][k_], xv[k_], a_);                                 \
      sr[h_] = a_;                                                           \
    }                                                                        \
    _Pragma("unroll") for (int h_ = 0; h_ < 6; h_++)                         \
        sr[h_] = wave_sum64(sr[h_]);                                         \
    bool upd_ = false;                                                       \
    _Pragma("unroll") for (int h_ = 0; h_ < 6; h_++)                         \
        upd_ = upd_ || (sr[h_] > m[h_] + 8.0f);                              \
    if (upd_) {                                                              \
      _Pragma("unroll") for (int h_ = 0; h_ < 6; h_++) {                     \
        const float nm_ = fmaxf(m[h_], sr[h_]);                              \
        const float f_ = __expf(m[h_] - nm_);                                \
        m[h_] = nm_;                                                         \
        l[h_] *= f_;                                                         \
        _Pragma("unroll") for (int k_ = 0; k_ < 6; k_++) acc[h_][k_] *= f_;  \
      }                                                                      \
    }                                                                        \
    _Pragma("unroll") for (int h_ = 0; h_ < 6; h_++) {                       \
      const float p_ = __expf(sr[h_] - m[h_]);                               \
      l[h_] += p_;                                                           \
      _Pragma("unroll") for (int k_ = 0; k_ < 6; k_++)                       \
          acc[h_][k_] = fmaf(p_, xv[k_], acc[h_][k_]);                       \
    }                                                                        \
  }

  if (cnt > 0) {
    LOADX(x0, 0);
    {
      const int i1 = (1 < cnt) ? 1 : (cnt - 1);
      LOADX(x1, i1);
    }
    int i = 0;
    while (true) {   // 3-buffer rotation, no register moves
      { const int ip = (i + 2 < cnt) ? i + 2 : cnt - 1; LOADX(x2, ip); }
      COMPUTE(x0);
      if (++i >= cnt) break;
      { const int ip = (i + 2 < cnt) ? i + 2 : cnt - 1; LOADX(x0, ip); }
      COMPUTE(x1);
      if (++i >= cnt) break;
      { const int ip = (i + 2 < cnt) ? i + 2 : cnt - 1; LOADX(x1, ip); }
      COMPUTE(x2);
      if (++i >= cnt) break;
    }
  }
#undef LOADX
#undef COMPUTE

  // ---- phase 2: cross-wave flash combine in LDS ----
  if (lane == 0) {
#pragma unroll
    for (int h = 0; h < 6; h++) {
      msh[w][h] = m[h];
      lsh[w][h] = l[h];
    }
  }
  __syncthreads();
  if (tid < 6) {
    const int h = tid;
    float M = -3.0e38f;
    for (int s = 0; s < 16; s++) M = fmaxf(M, msh[s][h]);
    float L = 0.f;
    for (int s = 0; s < 16; s++) {
      const float wv_ = __expf(msh[s][h] - M);
      wgts[s][h] = wv_;
      L += lsh[s][h] * wv_;
    }
    linv[h] = 1.0f / L;
  }
  __syncthreads();
  {
    float wg[6];
#pragma unroll
    for (int h = 0; h < 6; h++) wg[h] = wgts[w][h];
#pragma unroll
    for (int h = 0; h < 6; h++)
#pragma unroll
      for (int k = 0; k < 6; k++) acc[h][k] *= wg[h];
  }
  // accumulate into 4 slices over 4 barrier rounds (wave -> slice w&3)
  {
    float* xs = &xsl[w & 3][0];
    if (w < 4) {
#pragma unroll
      for (int h = 0; h < 6; h++) {
#pragma unroll
        for (int k = 0; k < 4; k++) xs[h * E + 4 * lane + k] = acc[h][k];
#pragma unroll
        for (int k = 4; k < 6; k++) xs[h * E + 256 + 2 * lane + (k - 4)] = acc[h][k];
      }
    }
    __syncthreads();
    if (w >= 4 && w < 8) {
#pragma unroll
      for (int h = 0; h < 6; h++) {
#pragma unroll
        for (int k = 0; k < 4; k++) xs[h * E + 4 * lane + k] += acc[h][k];
#pragma unroll
        for (int k = 4; k < 6; k++) xs[h * E + 256 + 2 * lane + (k - 4)] += acc[h][k];
      }
    }
    __syncthreads();
    if (w >= 8 && w < 12) {
#pragma unroll
      for (int h = 0; h < 6; h++) {
#pragma unroll
        for (int k = 0; k < 4; k++) xs[h * E + 4 * lane + k] += acc[h][k];
#pragma unroll
        for (int k = 4; k < 6; k++) xs[h * E + 256 + 2 * lane + (k - 4)] += acc[h][k];
      }
    }
    __syncthreads();
    if (w >= 12) {
#pragma unroll
      for (int h = 0; h < 6; h++) {
#pragma unroll
        for (int k = 0; k < 4; k++) xs[h * E + 4 * lane + k] += acc[h][k];
#pragma unroll
        for (int k = 4; k < 6; k++) xs[h * E + 256 + 2 * lane + (k - 4)] += acc[h][k];
      }
    }
    __syncthreads();
  }
  // tree-sum 4 slices + 1/L scale -> xsl[0]
  for (int idx = tid; idx < H * E; idx += 1024) {
    const int h = idx / E;
    xsl[0][idx] = ((xsl[0][idx] + xsl[1][idx]) + (xsl[2][idx] + xsl[3][idx]))
                  * linv[h];
  }
  __syncthreads();

  // ---- phase 3: GEMM chain (768 active threads; proven k3 stages) ----
  const float* xb = &xsl[0][0];
  const float* wvt = wsf + WS_WVT;
  const float* wot = wsf + WS_WOT;
  const float* wpt = wsf + WS_WPT;

  if (tid < 768) {  // stage 1: pooled[i] = Wv[i,:]·xb[head(i),:] + bv
    const int i = tid % 384, ks = tid / 384;
    const float* xh = xb + (i >> 6) * E + ks * 192;
    const float* wp_ = wvt + (size_t)(ks * 192) * E + i;
    float a0 = 0.f, a1 = 0.f, a2 = 0.f, a3 = 0.f;
#pragma unroll 4
    for (int e = 0; e < 192; e += 4) {
      a0 += wp_[(size_t)(e + 0) * E] * xh[e + 0];
      a1 += wp_[(size_t)(e + 1) * E] * xh[e + 1];
      a2 += wp_[(size_t)(e + 2) * E] * xh[e + 2];
      a3 += wp_[(size_t)(e + 3) * E] * xh[e + 3];
    }
    ps[tid] = (a0 + a1) + (a2 + a3);
  }
  __syncthreads();
  if (tid < 384) pooled[tid] = ps[tid] + ps[384 + tid] + bv[tid];
  __syncthreads();

  if (tid < 768) {  // stage 2: om[i] = Wo[i,:]·pooled + bo
    const int i = tid % 384, ks = tid / 384;
    const float* xh = pooled + ks * 192;
    const float* wp_ = wot + (size_t)(ks * 192) * E + i;
    float a0 = 0.f, a1 = 0.f, a2 = 0.f, a3 = 0.f;
#pragma unroll 4
    for (int e = 0; e < 192; e += 4) {
      a0 += wp_[(size_t)(e + 0) * E] * xh[e + 0];
      a1 += wp_[(size_t)(e + 1) * E] * xh[e + 1];
      a2 += wp_[(size_t)(e + 2) * E] * xh[e + 2];
      a3 += wp_[(size_t)(e + 3) * E] * xh[e + 3];
    }
    ps[tid] = (a0 + a1) + (a2 + a3);
  }
  __syncthreads();
  if (tid < 384) om[tid] = ps[tid] + ps[384 + tid] + bo[tid];
  __syncthreads();

  if (tid < 768) {  // stage 3: out[o] = Wp[o,:]·om + bp (3-way K-split)
    const int o = tid % 256, ks = tid / 256;
    const float* xh = om + ks * 128;
    const float* wp_ = wpt + (size_t)(ks * 128) * OUTD + o;
    float a0 = 0.f, a1 = 0.f, a2 = 0.f, a3 = 0.f;
#pragma unroll 4
    for (int e = 0; e < 128; e += 4) {
      a0 += wp_[(size_t)(e + 0) * OUTD] * xh[e + 0];
      a1 += wp_[(size_t)(e + 1) * OUTD] * xh[e + 1];
      a2 += wp_[(size_t)(e + 2) * OUTD] * xh[e + 2];
      a3 += wp_[(size_t)(e + 3) * OUTD] * xh[e + 3];
    }
    ps[tid] = (a0 + a1) + (a2 + a3);
  }
  __syncthreads();
  if (tid < 256)
    out[(size_t)g * OUTD + tid] = ps[tid] + ps[256 + tid] + ps[512 + tid] + bp[tid];
}

// ---------------------------------------------------------------------------
extern "C" void kernel_launch(void* const* d_in, const int* in_sizes, int n_in,
                              void* d_out, int out_size, void* d_ws, size_t ws_size,
                              hipStream_t stream) {
  const float* x     = (const float*)d_in[0];
  const int*   sizes = (const int*)d_in[1];
  const float* query = (const float*)d_in[2];
  const float* Wq    = (const float*)d_in[3];
  const float* bq    = (const float*)d_in[4];
  const float* Wk    = (const float*)d_in[5];
  const float* bk    = (const float*)d_in[6];  (void)bk;  // folded (shift-inv)
  const float* Wv    = (const float*)d_in[7];
  const float* bv    = (const float*)d_in[8];
  const float* Wo    = (const float*)d_in[9];
  const float* bo    = (const float*)d_in[10];
  const float* Wp    = (const float*)d_in[11];
  const float* bp    = (const float*)d_in[12];
  float* wsf = (float*)d_ws;
  float* out = (float*)d_out;

  hipLaunchKernelGGL(k_prep, dim3(133), dim3(256), 0, stream,
                     sizes, query, Wq, bq, Wk, Wv, Wo, Wp, wsf);
  hipLaunchKernelGGL(k12g_fused, dim3(G), dim3(1024), 0, stream,
                     x, sizes, bv, bo, bp, out, wsf);
}

// Round 5
// 773.725 us; speedup vs baseline: 1.2531x; 1.2531x over previous
//
#include <hip/hip_runtime.h>
#include <math.h>

// Problem constants (fixed-shape problem)
#define NN 131072   // nodes
#define G  256      // groups
#define E  384      // embed
#define H  6        // heads
#define DH 64       // head dim
#define OUTD 256    // output dim
#define MAXN 1024   // max segment length

#define SPLIT 4            // sub-blocks per group
#define PART_STRIDE 2316   // 6*384 acc + 6 m + 6 l

// Workspace layout (float indices)
#define WS_QK   0                       // 6*384 folded q@Wk
#define WS_OFF  2432                    // 256 int32 segment offsets
#define WS_PART 12288                   // G*SPLIT slots x 2316 partials (9.5 MB)
#define WS_WVT  (WS_PART + G*SPLIT*PART_STRIDE)  // 384x384 Wv^T [e][i]
#define WS_WOT  (WS_WVT + E*E)          // 384x384 Wo^T [e][i]
#define WS_WPT  (WS_WOT + E*E)          // 384x256 Wp^T [e][o]

// ---------------------------------------------------------------------------
// K_PREP: single launch, 133 blocks, three independent roles:
//   block 0      : segment-offset scan
//   blocks 1..36 : qk[h][e] = sum_d qv[h,d]*Wk[h*64+d][e]  (qv inline)
//   blocks 37..132: transpose Wv, Wo, Wp into ws (64x64 LDS tiles)
// ---------------------------------------------------------------------------
__global__ __launch_bounds__(256) void k_prep(
    const int* __restrict__ sizes, const float* __restrict__ query,
    const float* __restrict__ Wq, const float* __restrict__ bq,
    const float* __restrict__ Wk, const float* __restrict__ Wv,
    const float* __restrict__ Wo, const float* __restrict__ Wp,
    float* __restrict__ wsf) {
  const int b = blockIdx.x;
  const int tid = threadIdx.x;
  if (b == 0) {
    __shared__ int s_scan[G];
    const int sz = sizes[tid];
    s_scan[tid] = sz;
    __syncthreads();
    for (int d = 1; d < G; d <<= 1) {
      int t = (tid >= d) ? s_scan[tid - d] : 0;
      __syncthreads();
      s_scan[tid] += t;
      __syncthreads();
    }
    ((int*)(wsf + WS_OFF))[tid] = s_scan[tid] - sz;    // exclusive node offset
  } else if (b <= 36) {
    const int h = (b - 1) / 6, ec = (b - 1) % 6;
    __shared__ float qv_s[64];
    __shared__ float qps[256];
    __shared__ float ps[256];
    {  // inline qv rows h*64..h*64+63: thread (r,q) does a 96-elem quarter
      const int r = tid >> 2, q = tid & 3;
      const int row = h * 64 + r;
      float a = 0.f;
#pragma unroll 4
      for (int j = 0; j < 96; j++)
        a += Wq[(size_t)row * E + q * 96 + j] * query[q * 96 + j];
      qps[tid] = a;
    }
    __syncthreads();
    if (tid < 64)
      qv_s[tid] = 0.125f * (qps[tid * 4] + qps[tid * 4 + 1] +
                            qps[tid * 4 + 2] + qps[tid * 4 + 3] +
                            bq[h * 64 + tid]);
    __syncthreads();
    const int el = tid & 63, dq = tid >> 6;
    float a = 0.f;
#pragma unroll 4
    for (int d = dq * 16; d < dq * 16 + 16; d++)
      a += qv_s[d] * Wk[(size_t)(h * 64 + d) * E + ec * 64 + el];
    ps[tid] = a;
    __syncthreads();
    if (tid < 64)
      wsf[WS_QK + h * E + ec * 64 + tid] =
          ps[tid] + ps[64 + tid] + ps[128 + tid] + ps[192 + tid];
  } else {
    __shared__ float s[64][65];
    const int t = b - 37;                        // 0..95
    const float* src;
    float* dst;
    int R, tr, tc;
    if (t < 36)      { src = Wv; dst = wsf + WS_WVT; R = 384; tr = t / 6;        tc = t % 6; }
    else if (t < 72) { src = Wo; dst = wsf + WS_WOT; R = 384; tr = (t - 36) / 6; tc = (t - 36) % 6; }
    else             { src = Wp; dst = wsf + WS_WPT; R = 256; tr = (t - 72) / 6; tc = (t - 72) % 6; }
    const int r0 = tr * 64, c0 = tc * 64;
#pragma unroll
    for (int k = 0; k < 16; k++) {
      int idx = k * 256 + tid;
      int r = idx >> 6, cc = idx & 63;
      s[r][cc] = src[(size_t)(r0 + r) * E + c0 + cc];
    }
    __syncthreads();
#pragma unroll
    for (int k = 0; k < 16; k++) {
      int idx = k * 256 + tid;
      int cc = idx >> 6, r = idx & 63;
      dst[(size_t)(c0 + cc) * R + r0 + r] = s[r][cc];
    }
  }
}

// ---------------------------------------------------------------------------
// Wave-wide butterfly sum.  Steps xor1/2/4/8 via DPP (VALU pipe); xor16/32
// via shuffle (LDS pipe).
// ---------------------------------------------------------------------------
template <int CTRL>
__device__ __forceinline__ float dpp_radd(float v) {
  int t = __builtin_amdgcn_update_dpp(0, __float_as_int(v), CTRL, 0xf, 0xf, true);
  return v + __int_as_float(t);
}
__device__ __forceinline__ float wave_sum64(float v) {
  v = dpp_radd<0xB1>(v);   // quad_perm [1,0,3,2]  : xor 1
  v = dpp_radd<0x4E>(v);   // quad_perm [2,3,0,1]  : xor 2
  v = dpp_radd<0x141>(v);  // row_half_mirror      : xor 4
  v = dpp_radd<0x140>(v);  // row_mirror           : xor 8
  v += __shfl_xor(v, 16, 64);
  v += __shfl_xor(v, 32, 64);
  return v;
}

// ---------------------------------------------------------------------------
// K12S v10: per-QUARTER-group kernel.  Grid 1024 = G*4 contiguous quarter
// segments; 768 thr (12 waves), __launch_bounds__(768,3) -- the EXACT
// register regime round 3 proved spill-free (VGPR 68 + AGPR overflow, zero
// scratch).  v9 post-mortem: (1024,4) clamps budget to 128/wave -> 2 GB of
// scratch traffic.  Changes vs round-3 kernel:
//   - 4-way group split: CU critical path ~896 -> ~mean nodes (occupancy fix)
//   - depth-2 prefetch (3 rotating buffers, compile-time indices, scalar
//     dword loads k*64+lane -- the proven codegen)
//   - phase 2 combines the block's 12 waves, writes ONE partial slot
//     (2304 unnorm acc + m + l); k3c flash-combines the 4 slots per group.
// ---------------------------------------------------------------------------
__global__ __launch_bounds__(768, 3) void k12s_quarter(
    const float* __restrict__ x, const int* __restrict__ sizes,
    float* __restrict__ wsf) {
  __shared__ float xsl[4][H * E];      // 36.9 KB accumulation slices
  __shared__ float msh[12][H], lsh[12][H], wgts[12][H];
  __shared__ float Msh[H], Lsh[H];

  const int tid = threadIdx.x;
  const int lane = tid & 63;
  const int w = tid >> 6;              // wave 0..11
  const int b = blockIdx.x;
  const int g = b >> 2, q = b & 3;
  const int sz = sizes[g];
  const int qlen = (sz + 3) >> 2;
  const int start = q * qlen;
  int len = sz - start;
  if (len > qlen) len = qlen;
  if (len < 0) len = 0;
  const int n0 = ((const int*)(wsf + WS_OFF))[g] + start;

  // per-lane qk fragment: qk[h][k] pairs with column k*64+lane
  float qk[6][6];
#pragma unroll
  for (int h = 0; h < 6; h++)
#pragma unroll
    for (int k = 0; k < 6; k++) qk[h][k] = wsf[WS_QK + h * E + k * 64 + lane];

  float m[6], l[6], acc[6][6];
#pragma unroll
  for (int h = 0; h < 6; h++) {
    m[h] = -3.0e38f;
    l[h] = 0.f;
#pragma unroll
    for (int k = 0; k < 6; k++) acc[h][k] = 0.f;
  }

  // ---- phase 1: wave w handles quarter-local nodes w, w+12, w+24, ... ----
  const float* xp = x + (size_t)(n0 + w) * E + lane;
  const int cnt = (len > w) ? ((len - w + 11) / 12) : 0;

  float x0[6], x1[6], x2[6];
#define LOADX(buf, i)                                              \
  {                                                                \
    const float* p_ = xp + (size_t)(i) * (12 * E);                 \
    _Pragma("unroll") for (int k_ = 0; k_ < 6; k_++)               \
        buf[k_] = p_[k_ * 64];                                     \
  }
#define COMPUTE(xv)                                                          \
  {                                                                          \
    float sr[6];                                                             \
    _Pragma("unroll") for (int h_ = 0; h_ < 6; h_++) {                       \
      float a_ = qk[h_][0] * xv[0];                                          \
      _Pragma("unroll") for (int k_ = 1; k_ < 6; k_++)                       \
          a_ = fmaf(qk[h_][k_], xv[k_], a_);                                 \
      sr[h_] = a_;                                                           \
    }                                                                        \
    _Pragma("unroll") for (int h_ = 0; h_ < 6; h_++)                         \
        sr[h_] = wave_sum64(sr[h_]);                                         \
    bool upd_ = false;                                                       \
    _Pragma("unroll") for (int h_ = 0; h_ < 6; h_++)                         \
        upd_ = upd_ || (sr[h_] > m[h_] + 8.0f);                              \
    if (upd_) {                                                              \
      _Pragma("unroll") for (int h_ = 0; h_ < 6; h_++) {                     \
        const float nm_ = fmaxf(m[h_], sr[h_]);                              \
        const float f_ = __expf(m[h_] - nm_);                                \
        m[h_] = nm_;                                                         \
        l[h_] *= f_;                                                         \
        _Pragma("unroll") for (int k_ = 0; k_ < 6; k_++) acc[h_][k_] *= f_;  \
      }                                                                      \
    }                                                                        \
    _Pragma("unroll") for (int h_ = 0; h_ < 6; h_++) {                       \
      const float p_ = __expf(sr[h_] - m[h_]);                               \
      l[h_] += p_;                                                           \
      _Pragma("unroll") for (int k_ = 0; k_ < 6; k_++)                       \
          acc[h_][k_] = fmaf(p_, xv[k_], acc[h_][k_]);                       \
    }                                                                        \
  }

  if (cnt > 0) {
    LOADX(x0, 0);
    {
      const int i1 = (1 < cnt) ? 1 : (cnt - 1);
      LOADX(x1, i1);
    }
    int i = 0;
    while (true) {   // 3-buffer rotation, compile-time indices only
      { const int ip = (i + 2 < cnt) ? i + 2 : cnt - 1; LOADX(x2, ip); }
      COMPUTE(x0);
      if (++i >= cnt) break;
      { const int ip = (i + 2 < cnt) ? i + 2 : cnt - 1; LOADX(x0, ip); }
      COMPUTE(x1);
      if (++i >= cnt) break;
      { const int ip = (i + 2 < cnt) ? i + 2 : cnt - 1; LOADX(x1, ip); }
      COMPUTE(x2);
      if (++i >= cnt) break;
    }
  }
#undef LOADX
#undef COMPUTE

  // ---- phase 2: combine the block's 12 waves; keep acc UNNORMALIZED ----
  if (lane == 0) {
#pragma unroll
    for (int h = 0; h < 6; h++) {
      msh[w][h] = m[h];
      lsh[w][h] = l[h];
    }
  }
  __syncthreads();
  if (tid < 6) {
    const int h = tid;
    float M = -3.0e38f;
    for (int s = 0; s < 12; s++) M = fmaxf(M, msh[s][h]);
    float L = 0.f;
    for (int s = 0; s < 12; s++) {
      const float wv_ = __expf(msh[s][h] - M);
      wgts[s][h] = wv_;
      L += lsh[s][h] * wv_;
    }
    Msh[h] = M;
    Lsh[h] = L;
  }
  __syncthreads();
  {
    float wg[6];
#pragma unroll
    for (int h = 0; h < 6; h++) wg[h] = wgts[w][h];
#pragma unroll
    for (int h = 0; h < 6; h++)
#pragma unroll
      for (int k = 0; k < 6; k++) acc[h][k] *= wg[h];
  }
  // accumulate into 4 slices: round 0 waves 0-3 store, rounds 1-2 add
  {
    float* xs = &xsl[w & 3][0];
    if (w < 4) {
#pragma unroll
      for (int h = 0; h < 6; h++)
#pragma unroll
        for (int k = 0; k < 6; k++) xs[h * E + k * 64 + lane] = acc[h][k];
    }
    __syncthreads();
    if (w >= 4 && w < 8) {
#pragma unroll
      for (int h = 0; h < 6; h++)
#pragma unroll
        for (int k = 0; k < 6; k++) xs[h * E + k * 64 + lane] += acc[h][k];
    }
    __syncthreads();
    if (w >= 8) {
#pragma unroll
      for (int h = 0; h < 6; h++)
#pragma unroll
        for (int k = 0; k < 6; k++) xs[h * E + k * 64 + lane] += acc[h][k];
    }
    __syncthreads();
  }
  // tree-sum 4 slices -> partial slot (coalesced dword stores)
  float* pslot = wsf + WS_PART + (size_t)b * PART_STRIDE;
  for (int idx = tid; idx < H * E; idx += 768) {
    pslot[idx] = (xsl[0][idx] + xsl[1][idx]) + (xsl[2][idx] + xsl[3][idx]);
  }
  if (tid < 6) {
    pslot[2304 + tid] = Msh[tid];
    pslot[2310 + tid] = Lsh[tid];
  }
}

// ---------------------------------------------------------------------------
// K3C: one block (768 thr) per group.  Flash-combine the 4 quarter partials
// -> xb; then the proven 3-stage GEMM chain on transposed weights.
// ---------------------------------------------------------------------------
__global__ __launch_bounds__(768) void k3c_group(
    const float* __restrict__ wsf,
    const float* __restrict__ bv, const float* __restrict__ bo,
    const float* __restrict__ bp, float* __restrict__ out) {
  __shared__ float xb[H * E];          // 9.2 KB
  __shared__ float pooled[E];
  __shared__ float om[E];
  __shared__ float ps[768];
  __shared__ float msh[SPLIT][H], lsh[SPLIT][H], wgt[SPLIT][H];
  __shared__ float linv[H];
  const int tid = threadIdx.x;
  const int g = blockIdx.x;
  const float* pg = wsf + WS_PART + (size_t)(g * SPLIT) * PART_STRIDE;
  const float* wvt = wsf + WS_WVT;
  const float* wot = wsf + WS_WOT;
  const float* wpt = wsf + WS_WPT;

  if (tid < SPLIT * H) {
    const int s2 = tid / H, h2 = tid % H;
    msh[s2][h2] = pg[(size_t)s2 * PART_STRIDE + 2304 + h2];
    lsh[s2][h2] = pg[(size_t)s2 * PART_STRIDE + 2310 + h2];
  }
  __syncthreads();
  if (tid < H) {
    float M = -3.0e38f;
    for (int s = 0; s < SPLIT; s++) M = fmaxf(M, msh[s][tid]);
    float L = 0.f;
    for (int s = 0; s < SPLIT; s++) {
      const float wv_ = __expf(msh[s][tid] - M);
      wgt[s][tid] = wv_;
      L += lsh[s][tid] * wv_;
    }
    linv[tid] = 1.f / L;
  }
  __syncthreads();
  for (int idx = tid; idx < H * E; idx += 768) {
    const int h = idx / E;
    const float* pp = pg + idx;
    float a = pp[0] * wgt[0][h];
    a += pp[(size_t)1 * PART_STRIDE] * wgt[1][h];
    a += pp[(size_t)2 * PART_STRIDE] * wgt[2][h];
    a += pp[(size_t)3 * PART_STRIDE] * wgt[3][h];
    xb[idx] = a * linv[h];
  }
  __syncthreads();

  {  // stage 1: pooled[i] = Wv[i,:]·xb[head(i),:] + bv
    const int i = tid % 384, ks = tid / 384;
    const float* xh = xb + (i >> 6) * E + ks * 192;
    const float* wp_ = wvt + (size_t)(ks * 192) * E + i;
    float a0 = 0.f, a1 = 0.f, a2 = 0.f, a3 = 0.f;
#pragma unroll 4
    for (int e = 0; e < 192; e += 4) {
      a0 += wp_[(size_t)(e + 0) * E] * xh[e + 0];
      a1 += wp_[(size_t)(e + 1) * E] * xh[e + 1];
      a2 += wp_[(size_t)(e + 2) * E] * xh[e + 2];
      a3 += wp_[(size_t)(e + 3) * E] * xh[e + 3];
    }
    ps[tid] = (a0 + a1) + (a2 + a3);
  }
  __syncthreads();
  if (tid < 384) pooled[tid] = ps[tid] + ps[384 + tid] + bv[tid];
  __syncthreads();

  {  // stage 2: om[i] = Wo[i,:]·pooled + bo
    const int i = tid % 384, ks = tid / 384;
    const float* xh = pooled + ks * 192;
    const float* wp_ = wot + (size_t)(ks * 192) * E + i;
    float a0 = 0.f, a1 = 0.f, a2 = 0.f, a3 = 0.f;
#pragma unroll 4
    for (int e = 0; e < 192; e += 4) {
      a0 += wp_[(size_t)(e + 0) * E] * xh[e + 0];
      a1 += wp_[(size_t)(e + 1) * E] * xh[e + 1];
      a2 += wp_[(size_t)(e + 2) * E] * xh[e + 2];
      a3 += wp_[(size_t)(e + 3) * E] * xh[e + 3];
    }
    ps[tid] = (a0 + a1) + (a2 + a3);
  }
  __syncthreads();
  if (tid < 384) om[tid] = ps[tid] + ps[384 + tid] + bo[tid];
  __syncthreads();

  {  // stage 3: out[o] = Wp[o,:]·om + bp   (3-way K-split of 384)
    const int o = tid % 256, ks = tid / 256;
    const float* xh = om + ks * 128;
    const float* wp_ = wpt + (size_t)(ks * 128) * OUTD + o;
    float a0 = 0.f, a1 = 0.f, a2 = 0.f, a3 = 0.f;
#pragma unroll 4
    for (int e = 0; e < 128; e += 4) {
      a0 += wp_[(size_t)(e + 0) * OUTD] * xh[e + 0];
      a1 += wp_[(size_t)(e + 1) * OUTD] * xh[e + 1];
      a2 += wp_[(size_t)(e + 2) * OUTD] * xh[e + 2];
      a3 += wp_[(size_t)(e + 3) * OUTD] * xh[e + 3];
    }
    ps[tid] = (a0 + a1) + (a2 + a3);
  }
  __syncthreads();
  if (tid < 256)
    out[(size_t)g * OUTD + tid] = ps[tid] + ps[256 + tid] + ps[512 + tid] + bp[tid];
}

// ---------------------------------------------------------------------------
extern "C" void kernel_launch(void* const* d_in, const int* in_sizes, int n_in,
                              void* d_out, int out_size, void* d_ws, size_t ws_size,
                              hipStream_t stream) {
  const float* x     = (const float*)d_in[0];
  const int*   sizes = (const int*)d_in[1];
  const float* query = (const float*)d_in[2];
  const float* Wq    = (const float*)d_in[3];
  const float* bq    = (const float*)d_in[4];
  const float* Wk    = (const float*)d_in[5];
  const float* bk    = (const float*)d_in[6];  (void)bk;  // folded (shift-inv)
  const float* Wv    = (const float*)d_in[7];
  const float* bv    = (const float*)d_in[8];
  const float* Wo    = (const float*)d_in[9];
  const float* bo    = (const float*)d_in[10];
  const float* Wp    = (const float*)d_in[11];
  const float* bp    = (const float*)d_in[12];
  float* wsf = (float*)d_ws;
  float* out = (float*)d_out;

  hipLaunchKernelGGL(k_prep, dim3(133), dim3(256), 0, stream,
                     sizes, query, Wq, bq, Wk, Wv, Wo, Wp, wsf);
  hipLaunchKernelGGL(k12s_quarter, dim3(G * SPLIT), dim3(768), 0, stream,
                     x, sizes, wsf);
  hipLaunchKernelGGL(k3c_group, dim3(G), dim3(768), 0, stream,
                     wsf, bv, bo, bp, out);
}

// Round 6
// 337.193 us; speedup vs baseline: 2.8754x; 2.2946x over previous
//
#include <hip/hip_runtime.h>
#include <math.h>

// Problem constants (fixed-shape problem)
#define NN 131072   // nodes
#define G  256      // groups
#define E  384      // embed
#define H  6        // heads
#define DH 64       // head dim
#define OUTD 256    // output dim
#define MAXN 1024   // max segment length

#define SPLIT 4            // sub-blocks per group
#define PART_STRIDE 2316   // 6*384 acc + 6 m + 6 l

// Workspace layout (float indices)
#define WS_QK   0                       // 6*384 folded q@Wk
#define WS_OFF  2432                    // 256 int32 segment offsets
#define WS_PART 12288                   // G*SPLIT slots x 2316 partials (9.5 MB)
#define WS_WVT  (WS_PART + G*SPLIT*PART_STRIDE)  // 384x384 Wv^T [e][i]
#define WS_WOT  (WS_WVT + E*E)          // 384x384 Wo^T [e][i]
#define WS_WPT  (WS_WOT + E*E)          // 384x256 Wp^T [e][o]

// ---------------------------------------------------------------------------
// K_PREP: single launch, 133 blocks, three independent roles:
//   block 0      : segment-offset scan
//   blocks 1..36 : qk[h][e] = sum_d qv[h,d]*Wk[h*64+d][e]  (qv inline)
//   blocks 37..132: transpose Wv, Wo, Wp into ws (64x64 LDS tiles)
// ---------------------------------------------------------------------------
__global__ __launch_bounds__(256) void k_prep(
    const int* __restrict__ sizes, const float* __restrict__ query,
    const float* __restrict__ Wq, const float* __restrict__ bq,
    const float* __restrict__ Wk, const float* __restrict__ Wv,
    const float* __restrict__ Wo, const float* __restrict__ Wp,
    float* __restrict__ wsf) {
  const int b = blockIdx.x;
  const int tid = threadIdx.x;
  if (b == 0) {
    __shared__ int s_scan[G];
    const int sz = sizes[tid];
    s_scan[tid] = sz;
    __syncthreads();
    for (int d = 1; d < G; d <<= 1) {
      int t = (tid >= d) ? s_scan[tid - d] : 0;
      __syncthreads();
      s_scan[tid] += t;
      __syncthreads();
    }
    ((int*)(wsf + WS_OFF))[tid] = s_scan[tid] - sz;    // exclusive node offset
  } else if (b <= 36) {
    const int h = (b - 1) / 6, ec = (b - 1) % 6;
    __shared__ float qv_s[64];
    __shared__ float qps[256];
    __shared__ float ps[256];
    {  // inline qv rows h*64..h*64+63: thread (r,q) does a 96-elem quarter
      const int r = tid >> 2, q = tid & 3;
      const int row = h * 64 + r;
      float a = 0.f;
#pragma unroll 4
      for (int j = 0; j < 96; j++)
        a += Wq[(size_t)row * E + q * 96 + j] * query[q * 96 + j];
      qps[tid] = a;
    }
    __syncthreads();
    if (tid < 64)
      qv_s[tid] = 0.125f * (qps[tid * 4] + qps[tid * 4 + 1] +
                            qps[tid * 4 + 2] + qps[tid * 4 + 3] +
                            bq[h * 64 + tid]);
    __syncthreads();
    const int el = tid & 63, dq = tid >> 6;
    float a = 0.f;
#pragma unroll 4
    for (int d = dq * 16; d < dq * 16 + 16; d++)
      a += qv_s[d] * Wk[(size_t)(h * 64 + d) * E + ec * 64 + el];
    ps[tid] = a;
    __syncthreads();
    if (tid < 64)
      wsf[WS_QK + h * E + ec * 64 + tid] =
          ps[tid] + ps[64 + tid] + ps[128 + tid] + ps[192 + tid];
  } else {
    __shared__ float s[64][65];
    const int t = b - 37;                        // 0..95
    const float* src;
    float* dst;
    int R, tr, tc;
    if (t < 36)      { src = Wv; dst = wsf + WS_WVT; R = 384; tr = t / 6;        tc = t % 6; }
    else if (t < 72) { src = Wo; dst = wsf + WS_WOT; R = 384; tr = (t - 36) / 6; tc = (t - 36) % 6; }
    else             { src = Wp; dst = wsf + WS_WPT; R = 256; tr = (t - 72) / 6; tc = (t - 72) % 6; }
    const int r0 = tr * 64, c0 = tc * 64;
#pragma unroll
    for (int k = 0; k < 16; k++) {
      int idx = k * 256 + tid;
      int r = idx >> 6, cc = idx & 63;
      s[r][cc] = src[(size_t)(r0 + r) * E + c0 + cc];
    }
    __syncthreads();
#pragma unroll
    for (int k = 0; k < 16; k++) {
      int idx = k * 256 + tid;
      int cc = idx >> 6, r = idx & 63;
      dst[(size_t)(c0 + cc) * R + r0 + r] = s[r][cc];
    }
  }
}

// ---------------------------------------------------------------------------
// Wave-wide butterfly sum.  Steps xor1/2/4/8 via DPP (VALU pipe); xor16/32
// via shuffle (LDS pipe).
// ---------------------------------------------------------------------------
template <int CTRL>
__device__ __forceinline__ float dpp_radd(float v) {
  int t = __builtin_amdgcn_update_dpp(0, __float_as_int(v), CTRL, 0xf, 0xf, true);
  return v + __int_as_float(t);
}
__device__ __forceinline__ float wave_sum64(float v) {
  v = dpp_radd<0xB1>(v);   // quad_perm [1,0,3,2]  : xor 1
  v = dpp_radd<0x4E>(v);   // quad_perm [2,3,0,1]  : xor 2
  v = dpp_radd<0x141>(v);  // row_half_mirror      : xor 4
  v = dpp_radd<0x140>(v);  // row_mirror           : xor 8
  v += __shfl_xor(v, 16, 64);
  v += __shfl_xor(v, 32, 64);
  return v;
}

// ---------------------------------------------------------------------------
// K12S v11: per-QUARTER-group kernel.  Phase 1 + phase 2 are ROUND-3's
// spill-free code VERBATIM (VGPR 68, WRITE 256 KB measured): 12 waves,
// depth-1 ping-pong, scalar dword loads k*64+lane, identical COMPUTE macro,
// identical 4-slice LDS combine.  v10 post-mortem: the ONLY hot-loop change
// (3rd prefetch buffer) re-triggered the scratch spill (423 MB writes) --
// this state sits at the allocator cliff; do not perturb the live set.
// Only deltas vs round 3: quarter-segment indexing (outside hot loop) and
// the tree-sum writes UNNORMALIZED slice sum + M/L to a partial slot
// (k3c does the 4-slot flash combine + GEMM chain).
// ---------------------------------------------------------------------------
__global__ __launch_bounds__(768, 3) void k12s_quarter(
    const float* __restrict__ x, const int* __restrict__ sizes,
    float* __restrict__ wsf) {
  __shared__ float xsl[4][H * E];      // 36.9 KB accumulation slices
  __shared__ float msh[12][H], lsh[12][H], wgts[12][H];
  __shared__ float Msh[H], Lsh[H];

  const int tid = threadIdx.x;
  const int lane = tid & 63;
  const int w = tid >> 6;              // wave 0..11
  const int b = blockIdx.x;
  const int g = b >> 2, q = b & 3;
  const int sz = sizes[g];
  const int qlen = (sz + 3) >> 2;
  const int start = q * qlen;
  int len = sz - start;
  if (len > qlen) len = qlen;
  if (len < 0) len = 0;
  const int n0 = ((const int*)(wsf + WS_OFF))[g] + start;

  // per-lane qk fragment: qk[h][k] pairs with column k*64+lane
  float qk[6][6];
#pragma unroll
  for (int h = 0; h < 6; h++)
#pragma unroll
    for (int k = 0; k < 6; k++) qk[h][k] = wsf[WS_QK + h * E + k * 64 + lane];

  float m[6], l[6], acc[6][6];
#pragma unroll
  for (int h = 0; h < 6; h++) {
    m[h] = -3.0e38f;
    l[h] = 0.f;
#pragma unroll
    for (int k = 0; k < 6; k++) acc[h][k] = 0.f;
  }

  // ---- phase 1 (round-3 verbatim): wave w -> local nodes w, w+12, ... ----
  const float* xp = x + (size_t)(n0 + w) * E + lane;
  const int cnt = (len > w) ? ((len - w + 11) / 12) : 0;

  float x0[6], x1[6];
#define LOADX(buf, i)                                              \
  {                                                                \
    const float* p_ = xp + (size_t)(i) * (12 * E);                 \
    _Pragma("unroll") for (int k_ = 0; k_ < 6; k_++)               \
        buf[k_] = p_[k_ * 64];                                     \
  }
#define COMPUTE(xv)                                                          \
  {                                                                          \
    float sr[6];                                                             \
    _Pragma("unroll") for (int h_ = 0; h_ < 6; h_++) {                       \
      float a_ = qk[h_][0] * xv[0];                                          \
      _Pragma("unroll") for (int k_ = 1; k_ < 6; k_++)                       \
          a_ = fmaf(qk[h_][k_], xv[k_], a_);                                 \
      sr[h_] = a_;                                                           \
    }                                                                        \
    _Pragma("unroll") for (int h_ = 0; h_ < 6; h_++)                         \
        sr[h_] = wave_sum64(sr[h_]);                                         \
    bool upd_ = false;                                                       \
    _Pragma("unroll") for (int h_ = 0; h_ < 6; h_++)                         \
        upd_ = upd_ || (sr[h_] > m[h_] + 8.0f);                              \
    if (upd_) {                                                              \
      _Pragma("unroll") for (int h_ = 0; h_ < 6; h_++) {                     \
        const float nm_ = fmaxf(m[h_], sr[h_]);                              \
        const float f_ = __expf(m[h_] - nm_);                                \
        m[h_] = nm_;                                                         \
        l[h_] *= f_;                                                         \
        _Pragma("unroll") for (int k_ = 0; k_ < 6; k_++) acc[h_][k_] *= f_;  \
      }                                                                      \
    }                                                                        \
    _Pragma("unroll") for (int h_ = 0; h_ < 6; h_++) {                       \
      const float p_ = __expf(sr[h_] - m[h_]);                               \
      l[h_] += p_;                                                           \
      _Pragma("unroll") for (int k_ = 0; k_ < 6; k_++)                       \
          acc[h_][k_] = fmaf(p_, xv[k_], acc[h_][k_]);                       \
    }                                                                        \
  }

  if (cnt > 0) {
    LOADX(x0, 0);
    int i = 0;
    while (true) {
      int ip = (i + 1 < cnt) ? i + 1 : i;    // clamped prefetch (L1 dup ok)
      LOADX(x1, ip);
      COMPUTE(x0);
      if (++i >= cnt) break;
      ip = (i + 1 < cnt) ? i + 1 : i;
      LOADX(x0, ip);
      COMPUTE(x1);
      if (++i >= cnt) break;
    }
  }
#undef LOADX
#undef COMPUTE

  // ---- phase 2 (round-3 verbatim, minus 1/L): cross-wave combine ----
  if (lane == 0) {
#pragma unroll
    for (int h = 0; h < 6; h++) {
      msh[w][h] = m[h];
      lsh[w][h] = l[h];
    }
  }
  __syncthreads();
  if (tid < 6) {
    const int h = tid;
    float M = -3.0e38f;
    for (int s = 0; s < 12; s++) M = fmaxf(M, msh[s][h]);
    float L = 0.f;
    for (int s = 0; s < 12; s++) {
      const float wv_ = __expf(msh[s][h] - M);
      wgts[s][h] = wv_;
      L += lsh[s][h] * wv_;
    }
    Msh[h] = M;
    Lsh[h] = L;
  }
  __syncthreads();
  {
    float wg[6];
#pragma unroll
    for (int h = 0; h < 6; h++) wg[h] = wgts[w][h];
#pragma unroll
    for (int h = 0; h < 6; h++)
#pragma unroll
      for (int k = 0; k < 6; k++) acc[h][k] *= wg[h];
  }
  // accumulate into 4 slices: round 0 waves 0-3 store, rounds 1-2 add
  {
    float* xs = &xsl[w & 3][0];
    if (w < 4) {
#pragma unroll
      for (int h = 0; h < 6; h++)
#pragma unroll
        for (int k = 0; k < 6; k++) xs[h * E + k * 64 + lane] = acc[h][k];
    }
    __syncthreads();
    if (w >= 4 && w < 8) {
#pragma unroll
      for (int h = 0; h < 6; h++)
#pragma unroll
        for (int k = 0; k < 6; k++) xs[h * E + k * 64 + lane] += acc[h][k];
    }
    __syncthreads();
    if (w >= 8) {
#pragma unroll
      for (int h = 0; h < 6; h++)
#pragma unroll
        for (int k = 0; k < 6; k++) xs[h * E + k * 64 + lane] += acc[h][k];
    }
    __syncthreads();
  }
  // tree-sum 4 slices -> UNNORMALIZED partial slot (coalesced dword stores)
  float* pslot = wsf + WS_PART + (size_t)b * PART_STRIDE;
  for (int idx = tid; idx < H * E; idx += 768) {
    pslot[idx] = (xsl[0][idx] + xsl[1][idx]) + (xsl[2][idx] + xsl[3][idx]);
  }
  if (tid < 6) {
    pslot[2304 + tid] = Msh[tid];
    pslot[2310 + tid] = Lsh[tid];
  }
}

// ---------------------------------------------------------------------------
// K3C: one block (768 thr) per group.  Flash-combine the 4 quarter partials
// -> xb; then the proven 3-stage GEMM chain on transposed weights.
// ---------------------------------------------------------------------------
__global__ __launch_bounds__(768) void k3c_group(
    const float* __restrict__ wsf,
    const float* __restrict__ bv, const float* __restrict__ bo,
    const float* __restrict__ bp, float* __restrict__ out) {
  __shared__ float xb[H * E];          // 9.2 KB
  __shared__ float pooled[E];
  __shared__ float om[E];
  __shared__ float ps[768];
  __shared__ float msh[SPLIT][H], lsh[SPLIT][H], wgt[SPLIT][H];
  __shared__ float linv[H];
  const int tid = threadIdx.x;
  const int g = blockIdx.x;
  const float* pg = wsf + WS_PART + (size_t)(g * SPLIT) * PART_STRIDE;
  const float* wvt = wsf + WS_WVT;
  const float* wot = wsf + WS_WOT;
  const float* wpt = wsf + WS_WPT;

  if (tid < SPLIT * H) {
    const int s2 = tid / H, h2 = tid % H;
    msh[s2][h2] = pg[(size_t)s2 * PART_STRIDE + 2304 + h2];
    lsh[s2][h2] = pg[(size_t)s2 * PART_STRIDE + 2310 + h2];
  }
  __syncthreads();
  if (tid < H) {
    float M = -3.0e38f;
    for (int s = 0; s < SPLIT; s++) M = fmaxf(M, msh[s][tid]);
    float L = 0.f;
    for (int s = 0; s < SPLIT; s++) {
      const float wv_ = __expf(msh[s][tid] - M);
      wgt[s][tid] = wv_;
      L += lsh[s][tid] * wv_;
    }
    linv[tid] = 1.f / L;
  }
  __syncthreads();
  for (int idx = tid; idx < H * E; idx += 768) {
    const int h = idx / E;
    const float* pp = pg + idx;
    float a = pp[0] * wgt[0][h];
    a += pp[(size_t)1 * PART_STRIDE] * wgt[1][h];
    a += pp[(size_t)2 * PART_STRIDE] * wgt[2][h];
    a += pp[(size_t)3 * PART_STRIDE] * wgt[3][h];
    xb[idx] = a * linv[h];
  }
  __syncthreads();

  {  // stage 1: pooled[i] = Wv[i,:]·xb[head(i),:] + bv
    const int i = tid % 384, ks = tid / 384;
    const float* xh = xb + (i >> 6) * E + ks * 192;
    const float* wp_ = wvt + (size_t)(ks * 192) * E + i;
    float a0 = 0.f, a1 = 0.f, a2 = 0.f, a3 = 0.f;
#pragma unroll 4
    for (int e = 0; e < 192; e += 4) {
      a0 += wp_[(size_t)(e + 0) * E] * xh[e + 0];
      a1 += wp_[(size_t)(e + 1) * E] * xh[e + 1];
      a2 += wp_[(size_t)(e + 2) * E] * xh[e + 2];
      a3 += wp_[(size_t)(e + 3) * E] * xh[e + 3];
    }
    ps[tid] = (a0 + a1) + (a2 + a3);
  }
  __syncthreads();
  if (tid < 384) pooled[tid] = ps[tid] + ps[384 + tid] + bv[tid];
  __syncthreads();

  {  // stage 2: om[i] = Wo[i,:]·pooled + bo
    const int i = tid % 384, ks = tid / 384;
    const float* xh = pooled + ks * 192;
    const float* wp_ = wot + (size_t)(ks * 192) * E + i;
    float a0 = 0.f, a1 = 0.f, a2 = 0.f, a3 = 0.f;
#pragma unroll 4
    for (int e = 0; e < 192; e += 4) {
      a0 += wp_[(size_t)(e + 0) * E] * xh[e + 0];
      a1 += wp_[(size_t)(e + 1) * E] * xh[e + 1];
      a2 += wp_[(size_t)(e + 2) * E] * xh[e + 2];
      a3 += wp_[(size_t)(e + 3) * E] * xh[e + 3];
    }
    ps[tid] = (a0 + a1) + (a2 + a3);
  }
  __syncthreads();
  if (tid < 384) om[tid] = ps[tid] + ps[384 + tid] + bo[tid];
  __syncthreads();

  {  // stage 3: out[o] = Wp[o,:]·om + bp   (3-way K-split of 384)
    const int o = tid % 256, ks = tid / 256;
    const float* xh = om + ks * 128;
    const float* wp_ = wpt + (size_t)(ks * 128) * OUTD + o;
    float a0 = 0.f, a1 = 0.f, a2 = 0.f, a3 = 0.f;
#pragma unroll 4
    for (int e = 0; e < 128; e += 4) {
      a0 += wp_[(size_t)(e + 0) * OUTD] * xh[e + 0];
      a1 += wp_[(size_t)(e + 1) * OUTD] * xh[e + 1];
      a2 += wp_[(size_t)(e + 2) * OUTD] * xh[e + 2];
      a3 += wp_[(size_t)(e + 3) * OUTD] * xh[e + 3];
    }
    ps[tid] = (a0 + a1) + (a2 + a3);
  }
  __syncthreads();
  if (tid < 256)
    out[(size_t)g * OUTD + tid] = ps[tid] + ps[256 + tid] + ps[512 + tid] + bp[tid];
}

// ---------------------------------------------------------------------------
extern "C" void kernel_launch(void* const* d_in, const int* in_sizes, int n_in,
                              void* d_out, int out_size, void* d_ws, size_t ws_size,
                              hipStream_t stream) {
  const float* x     = (const float*)d_in[0];
  const int*   sizes = (const int*)d_in[1];
  const float* query = (const float*)d_in[2];
  const float* Wq    = (const float*)d_in[3];
  const float* bq    = (const float*)d_in[4];
  const float* Wk    = (const float*)d_in[5];
  const float* bk    = (const float*)d_in[6];  (void)bk;  // folded (shift-inv)
  const float* Wv    = (const float*)d_in[7];
  const float* bv    = (const float*)d_in[8];
  const float* Wo    = (const float*)d_in[9];
  const float* bo    = (const float*)d_in[10];
  const float* Wp    = (const float*)d_in[11];
  const float* bp    = (const float*)d_in[12];
  float* wsf = (float*)d_ws;
  float* out = (float*)d_out;

  hipLaunchKernelGGL(k_prep, dim3(133), dim3(256), 0, stream,
                     sizes, query, Wq, bq, Wk, Wv, Wo, Wp, wsf);
  hipLaunchKernelGGL(k12s_quarter, dim3(G * SPLIT), dim3(768), 0, stream,
                     x, sizes, wsf);
  hipLaunchKernelGGL(k3c_group, dim3(G), dim3(768), 0, stream,
                     wsf, bv, bo, bp, out);
}